// Round 1
// baseline (109.367 us; speedup 1.0000x reference)
//
#include <hip/hip_runtime.h>
#include <math.h>

// B=256; bilinear upsample 64/32/16 -> 256x256 (align_corners=True), sum -> maps;
// 5x5 gaussian blur (sigma=4, reflect); per-sample max -> scores.
//
// v2 structure: grid = B*4 blocks x 256 threads (4 waves). Each WAVE independently
// owns a 16-row output strip: 64 lanes x 4 columns (float4 everywhere).
//   - inputs staged whole to LDS (21 KB), one barrier total
//   - rolling separable bilinear per column-quad; rolling control (rem/y) kept
//     wave-uniform in SGPRs via readfirstlane(waveid)
//   - vertical 5-tap in a float4 register window (no LDS round-trip)
//   - horizontal 5-tap via in-wave __shfl to fetch neighbor-quad edge columns
//   - float4 stores to maps; wave shuffle-reduce max -> partials
// Kernel 2: partials -> scores (deterministic).

static constexpr int W  = 256;
static constexpr int QH = 4;   // blocks per sample (64 rows each; 16 rows per wave)

__device__ __forceinline__ int reflect256(int i) {
    if (i < 0) i = -i;
    if (i > 255) i = 510 - i;
    return i;
}

__global__ __launch_bounds__(256, 4) void fused_kernel(
    const float* __restrict__ in0,   // [B,64,64]
    const float* __restrict__ in1,   // [B,32,32]
    const float* __restrict__ in2,   // [B,16,16]
    float* __restrict__ part,        // [B*QH] partial maxes
    float* __restrict__ maps)        // [B,256,256]
{
    const int t   = threadIdx.x;
    const int q   = t & 63;                                      // lane = column quad
    const int wv  = __builtin_amdgcn_readfirstlane(t >> 6);      // wave id (SGPR)
    const int bid = blockIdx.x;
    const int b   = bid >> 2;
    const int r0  = (bid & 3) * 64;
    const int rw0 = r0 + wv * 16;                                // this wave's first output row
    const int c0  = q * 4;                                       // first column of quad

    __shared__ float s0[64 * 64];    // 16 KB
    __shared__ float s1[32 * 32];    // 4 KB
    __shared__ float s2[16 * 16];    // 1 KB
    __shared__ float red[4];

    // ---- stage inputs (float4) ----
    {
        const float4* g0 = (const float4*)(in0 + (size_t)b * 4096);
        const float4* g1 = (const float4*)(in1 + (size_t)b * 1024);
        const float4* g2 = (const float4*)(in2 + (size_t)b * 256);
        float4* l0 = (float4*)s0;
        float4* l1 = (float4*)s1;
        float4* l2 = (float4*)s2;
#pragma unroll
        for (int i = 0; i < 4; ++i) l0[t + i * 256] = g0[t + i * 256];
        l1[t] = g1[t];
        if (t < 64) l2[t] = g2[t];
    }
    __syncthreads();

    // ---- per-column x-interp params (integer-exact), 4 columns per thread ----
    const float inv255 = 1.0f / 255.0f;
    int x00[4]; float fx0[4];
    int x10[4]; float fx1[4];
    int x20[4]; float fx2[4];
#pragma unroll
    for (int k = 0; k < 4; ++k) {
        const int c = c0 + k;
        int ix = c * 63; x00[k] = ix / 255; fx0[k] = (float)(ix - 255 * x00[k]) * inv255;
        ix = c * 31;     x10[k] = ix / 255; fx1[k] = (float)(ix - 255 * x10[k]) * inv255;
        ix = c * 15;     x20[k] = ix / 255; fx2[k] = (float)(ix - 255 * x20[k]) * inv255;
    }

    // x-interpolate one source row into a 4-col register vector
    auto xq0 = [&](int y, float* o) {
        const float* row = s0 + y * 64;
#pragma unroll
        for (int k = 0; k < 4; ++k) {
            int xa = x00[k], xb = min(xa + 1, 63);
            float a = row[xa], bb = row[xb];
            o[k] = a + fx0[k] * (bb - a);
        }
    };
    auto xq1 = [&](int y, float* o) {
        const float* row = s1 + y * 32;
#pragma unroll
        for (int k = 0; k < 4; ++k) {
            int xa = x10[k], xb = min(xa + 1, 31);
            float a = row[xa], bb = row[xb];
            o[k] = a + fx1[k] * (bb - a);
        }
    };
    auto xq2 = [&](int y, float* o) {
        const float* row = s2 + y * 16;
#pragma unroll
        for (int k = 0; k < 4; ++k) {
            int xa = x20[k], xb = min(xa + 1, 15);
            float a = row[xa], bb = row[xb];
            o[k] = a + fx2[k] * (bb - a);
        }
    };

    // full bilinear sample of map row rn (reflected), 4 cols
    auto direct4 = [&](int rn, float* o) {
        const int ry = reflect256(rn);
        int iy0 = ry * 63; int ya0 = iy0 / 255; float fya = (float)(iy0 - 255 * ya0) * inv255; int ya1 = min(ya0 + 1, 63);
        int iy1 = ry * 31; int yb0 = iy1 / 255; float fyb = (float)(iy1 - 255 * yb0) * inv255; int yb1 = min(yb0 + 1, 31);
        int iy2 = ry * 15; int yc0 = iy2 / 255; float fyc = (float)(iy2 - 255 * yc0) * inv255; int yc1 = min(yc0 + 1, 15);
        const float* r0a = s0 + ya0 * 64; const float* r0b = s0 + ya1 * 64;
        const float* r1a = s1 + yb0 * 32; const float* r1b = s1 + yb1 * 32;
        const float* r2a = s2 + yc0 * 16; const float* r2b = s2 + yc1 * 16;
#pragma unroll
        for (int k = 0; k < 4; ++k) {
            int xa = x00[k], xb = min(xa + 1, 63);
            float a = r0a[xa], bv = r0a[xb], cv = r0b[xa], dv = r0b[xb];
            float top = a + fx0[k] * (bv - a);
            float bot = cv + fx0[k] * (dv - cv);
            float v = top + fya * (bot - top);
            xa = x10[k]; xb = min(xa + 1, 31);
            a = r1a[xa]; bv = r1a[xb]; cv = r1b[xa]; dv = r1b[xb];
            top = a + fx1[k] * (bv - a);
            bot = cv + fx1[k] * (dv - cv);
            v += top + fyb * (bot - top);
            xa = x20[k]; xb = min(xa + 1, 15);
            a = r2a[xa]; bv = r2a[xb]; cv = r2b[xa]; dv = r2b[xb];
            top = a + fx2[k] * (bv - a);
            bot = cv + fx2[k] * (dv - cv);
            v += top + fyc * (bot - top);
            o[k] = v;
        }
    };

    // ---- gaussian weights (ksize=5, sigma=4) ----
    const float e1 = expf(-1.0f / 32.0f);
    const float e2 = expf(-4.0f / 32.0f);
    const float nrm = 1.0f + 2.0f * e1 + 2.0f * e2;
    const float gwc = 1.0f / nrm, gwa = e1 / nrm, gwb = e2 / nrm;

    // ---- prime 4-row window: map rows rw0-2 .. rw0+1 ----
    float m0[4], m1[4], m2[4], m3[4], mn[4];
    direct4(rw0 - 2, m0);
    direct4(rw0 - 1, m1);
    direct4(rw0,     m2);
    direct4(rw0 + 1, m3);

    float* __restrict__ mpr = maps + ((size_t)b * W + (size_t)rw0) * W + c0;
    *(float4*)(mpr)     = make_float4(m2[0], m2[1], m2[2], m2[3]);
    *(float4*)(mpr + W) = make_float4(m3[0], m3[1], m3[2], m3[3]);

    // ---- rolling bilinear state at rn = rw0+2 (wave-uniform control in SGPRs) ----
    int iy, ya, yb, yc, rem0, rem1, rem2;
    float rlo0[4], rhi0[4], rlo1[4], rhi1[4], rlo2[4], rhi2[4];
    iy = (rw0 + 2) * 63; ya = iy / 255; rem0 = iy - 255 * ya; xq0(ya, rlo0); xq0(min(ya + 1, 63), rhi0);
    iy = (rw0 + 2) * 31; yb = iy / 255; rem1 = iy - 255 * yb; xq1(yb, rlo1); xq1(min(yb + 1, 31), rhi1);
    iy = (rw0 + 2) * 15; yc = iy / 255; rem2 = iy - 255 * yc; xq2(yc, rlo2); xq2(min(yc + 1, 15), rhi2);

    float gmax = -INFINITY;

#pragma unroll 4
    for (int i = 0; i < 16; ++i) {
        const int rn = rw0 + 2 + i;          // new map row
        if (rn <= 255) {
            const float w0 = (float)rem0 * inv255;
            const float w1 = (float)rem1 * inv255;
            const float w2 = (float)rem2 * inv255;
#pragma unroll
            for (int k = 0; k < 4; ++k) {
                float v0 = rlo0[k] + w0 * (rhi0[k] - rlo0[k]);
                float v1 = rlo1[k] + w1 * (rhi1[k] - rlo1[k]);
                float v2 = rlo2[k] + w2 * (rhi2[k] - rlo2[k]);
                mn[k] = v0 + v1 + v2;
            }
            // advance (wave-uniform; step < 1 so at most one increment)
            rem0 += 63;
            if (rem0 >= 255) {
                rem0 -= 255; ++ya;
#pragma unroll
                for (int k = 0; k < 4; ++k) rlo0[k] = rhi0[k];
                xq0(min(ya + 1, 63), rhi0);
            }
            rem1 += 31;
            if (rem1 >= 255) {
                rem1 -= 255; ++yb;
#pragma unroll
                for (int k = 0; k < 4; ++k) rlo1[k] = rhi1[k];
                xq1(min(yb + 1, 31), rhi1);
            }
            rem2 += 15;
            if (rem2 >= 255) {
                rem2 -= 255; ++yc;
#pragma unroll
                for (int k = 0; k < 4; ++k) rlo2[k] = rhi2[k];
                xq2(min(yc + 1, 15), rhi2);
            }
        } else {
            direct4(rn, mn);                 // reflected rows 256/257 (top strip only)
        }

        if (i < 14)                          // rows rw0+2 .. rw0+15 are ours
            *(float4*)(mpr + (size_t)(2 + i) * W) = make_float4(mn[0], mn[1], mn[2], mn[3]);

        // vertical 5-tap for blur row rn-2 (in registers)
        float vr0 = gwb * (m0[0] + mn[0]) + gwa * (m1[0] + m3[0]) + gwc * m2[0];
        float vr1 = gwb * (m0[1] + mn[1]) + gwa * (m1[1] + m3[1]) + gwc * m2[1];
        float vr2 = gwb * (m0[2] + mn[2]) + gwa * (m1[2] + m3[2]) + gwc * m2[2];
        float vr3 = gwb * (m0[3] + mn[3]) + gwa * (m1[3] + m3[3]) + gwc * m2[3];
#pragma unroll
        for (int k = 0; k < 4; ++k) { m0[k] = m1[k]; m1[k] = m2[k]; m2[k] = m3[k]; m3[k] = mn[k]; }

        // horizontal 5-tap: neighbor-quad edge columns via in-wave shuffles
        float az = __shfl_up(vr2, 1);        // col c0-2 from left lane
        float aw = __shfl_up(vr3, 1);        // col c0-1
        float cx = __shfl_down(vr0, 1);      // col c0+4 from right lane
        float cy = __shfl_down(vr1, 1);      // col c0+5
        float a2 = (q == 0)  ? vr2 : az;     // reflect at col 0
        float a3 = (q == 0)  ? vr1 : aw;
        float c4 = (q == 63) ? vr2 : cx;     // reflect at col 255
        float c5 = (q == 63) ? vr1 : cy;
        float o0 = gwc * vr0 + gwa * (a3 + vr1)  + gwb * (a2 + vr2);
        float o1 = gwc * vr1 + gwa * (vr0 + vr2) + gwb * (a3 + vr3);
        float o2 = gwc * vr2 + gwa * (vr1 + vr3) + gwb * (vr0 + c4);
        float o3 = gwc * vr3 + gwa * (vr2 + c4)  + gwb * (vr1 + c5);
        gmax = fmaxf(gmax, fmaxf(fmaxf(o0, o1), fmaxf(o2, o3)));
    }

    // ---- block max -> partial ----
#pragma unroll
    for (int off = 32; off > 0; off >>= 1)
        gmax = fmaxf(gmax, __shfl_down(gmax, off));
    if (q == 0) red[wv] = gmax;
    __syncthreads();
    if (t == 0)
        part[bid] = fmaxf(fmaxf(red[0], red[1]), fmaxf(red[2], red[3]));
}

__global__ void reduce_kernel(const float* __restrict__ part,
                              float* __restrict__ scores, int B) {
    int i = blockIdx.x * blockDim.x + threadIdx.x;
    if (i < B) {
        float m = part[QH * i];
#pragma unroll
        for (int k = 1; k < QH; ++k) m = fmaxf(m, part[QH * i + k]);
        scores[i] = m;
    }
}

extern "C" void kernel_launch(void* const* d_in, const int* in_sizes, int n_in,
                              void* d_out, int out_size, void* d_ws, size_t ws_size,
                              hipStream_t stream) {
    const float* in0 = (const float*)d_in[0];
    const float* in1 = (const float*)d_in[1];
    const float* in2 = (const float*)d_in[2];
    const int B = in_sizes[0] / (64 * 64);

    float* scores = (float*)d_out;
    float* maps   = (float*)d_out + B;
    float* part   = (float*)d_ws;          // B*QH floats, fully rewritten each call

    hipLaunchKernelGGL(fused_kernel, dim3(B * QH), dim3(256), 0, stream,
                       in0, in1, in2, part, maps);
    hipLaunchKernelGGL(reduce_kernel, dim3((B + 255) / 256), dim3(256), 0, stream,
                       part, scores, B);
}